// Round 8
// baseline (130.753 us; speedup 1.0000x reference)
//
#include <hip/hip_runtime.h>
#include <hip/hip_cooperative_groups.h>

namespace cg = cooperative_groups;

#define N_NODES 2048
#define WORDS   64          // N_NODES / 32
#define E_MAX_OUT 1048576
#define FDIM    8
#define GRID2   512         // cooperative grid: 2 blocks/CU on 256 CUs

// ws layout: a_bits(512K) | c_bits(512K) | rel_off(512K) | row_cnt(8K)

// ---------------- K1: fill whole output (-1 indices, 0 attrs) + zero a_bits ----------------
// R3-proven branch-free streaming fill: one linear float4 stream at ~6.4 TB/s.
__global__ void __launch_bounds__(256) k_init_fill(float* __restrict__ out,
                                                   unsigned* __restrict__ a_bits) {
    int tid = blockIdx.x * blockDim.x + threadIdx.x;
    int nth = gridDim.x * blockDim.x;
    const int TOTAL4 = (2 * E_MAX_OUT + FDIM * E_MAX_OUT) / 4;  // 2,621,440 float4
    const int NEG4   = (2 * E_MAX_OUT) / 4;                     // rows|cols = -1
    float4* o4 = (float4*)out;
    for (int p = tid; p < TOTAL4; p += nth) {
        float v = (p < NEG4) ? -1.0f : 0.0f;
        o4[p] = make_float4(v, v, v, v);
    }
    uint4* a4 = (uint4*)a_bits;
    for (int p = tid; p < N_NODES * WORDS / 4; p += nth)
        a4[p] = make_uint4(0u, 0u, 0u, 0u);
}

// ---------------- K2: cooperative build -> twohop -> scan+emit ----------------
__global__ void __launch_bounds__(256) k_fused(const int* __restrict__ ei,
                                               const float* __restrict__ attr, int E,
                                               unsigned* __restrict__ a_bits,
                                               unsigned* __restrict__ c_bits,
                                               int* __restrict__ rel_off,
                                               int* __restrict__ row_cnt,
                                               float* __restrict__ out) {
    cg::grid_group grid = cg::this_grid();
    int b    = blockIdx.x;
    int t    = threadIdx.x;
    int lane = t & 63;
    int wv   = t >> 6;

    __shared__ int nbr[4][256];
    __shared__ int ncnt_sh[4];
    __shared__ int s_roff[N_NODES];   // 8 KB
    __shared__ int wsum[4];

    // ---- phase 1: build adjacency bitset (first 128 blocks carry the edges) ----
    for (int e = b * 256 + t; e < E; e += GRID2 * 256) {
        int s = ei[e];
        int d = ei[E + e];
        atomicOr(&a_bits[s * WORDS + (d >> 5)], 1u << (d & 31));
    }
    grid.sync();

    // ---- phase 2: twohop, one row per wave (i = b*4 + wv), R3-proven body ----
    int i = b * 4 + wv;
    unsigned r = a_bits[i * WORDS + lane];
    int pc = __popc(r);
    int incl = pc;
    for (int off = 1; off < 64; off <<= 1) {
        int v = __shfl_up(incl, off, 64);
        if (lane >= off) incl += v;
    }
    int base = incl - pc;
    unsigned bits = r;
    int wb = lane << 5;
    while (bits) {
        int bb = __ffs(bits) - 1;
        bits &= bits - 1;
        nbr[wv][base++] = wb + bb;
    }
    if (lane == 63) ncnt_sh[wv] = incl;
    __syncthreads();

    int nc = ncnt_sh[wv];
    const int* nb = nbr[wv];
    unsigned acc = 0u;
    int j = 0;
    for (; j + 4 <= nc; j += 4) {
        unsigned x0 = a_bits[nb[j]     * WORDS + lane];
        unsigned x1 = a_bits[nb[j + 1] * WORDS + lane];
        unsigned x2 = a_bits[nb[j + 2] * WORDS + lane];
        unsigned x3 = a_bits[nb[j + 3] * WORDS + lane];
        acc |= (x0 | x1) | (x2 | x3);
    }
    for (; j < nc; ++j) acc |= a_bits[nb[j] * WORDS + lane];

    if (lane == (i >> 5)) acc &= ~(1u << (i & 31));  // remove self-loop (two-hop)
    acc |= r;                                         // union original edges
    c_bits[i * WORDS + lane] = acc;

    int cnt = __popc(acc);
    int incl2 = cnt;
    for (int off = 1; off < 64; off <<= 1) {
        int v = __shfl_up(incl2, off, 64);
        if (lane >= off) incl2 += v;
    }
    rel_off[i * WORDS + lane] = incl2 - cnt;   // within-row exclusive word offset
    if (lane == 63) row_cnt[i] = incl2;
    grid.sync();

    // ---- phase 3a: full 2048-point exclusive scan into LDS (per block, redundant) ----
    int vbase = t * (N_NODES / 256);          // 8 values per thread
    int v8[N_NODES / 256];
    int s = 0;
    #pragma unroll
    for (int q = 0; q < N_NODES / 256; ++q) { v8[q] = row_cnt[vbase + q]; s += v8[q]; }
    int sincl = s;
    for (int off = 1; off < 64; off <<= 1) {
        int v = __shfl_up(sincl, off, 64);
        if (lane >= off) sincl += v;
    }
    if (lane == 63) wsum[wv] = sincl;
    __syncthreads();
    int woff = 0;
    for (int w = 0; w < wv; ++w) woff += wsum[w];
    int run = woff + sincl - s;               // exclusive prefix at vbase
    #pragma unroll
    for (int q = 0; q < N_NODES / 256; ++q) { s_roff[vbase + q] = run; run += v8[q]; }
    __syncthreads();

    // ---- phase 3b: emit indices for row i (valid slots only; tail prefilled by K1) ----
    {
        unsigned c = c_bits[i * WORDS + lane];
        int p = s_roff[i] + rel_off[i * WORDS + lane];
        float fi = (float)i;
        while (c) {
            int bb = __ffs(c) - 1;
            c &= c - 1;
            out[p]             = fi;
            out[E_MAX_OUT + p] = (float)(wb + bb);
            ++p;
        }
    }

    // ---- phase 3c: attr scatter, 64 edges per block, 4 lanes per edge ----
    {
        float* oattr = out + 2 * E_MAX_OUT;
        int q = t & 3;
        for (int e = b * 64 + (t >> 2); e < E; e += GRID2 * 64) {
            int s2 = ei[e];
            int d  = ei[E + e];
            int dw = d >> 5;
            unsigned cw = c_bits[s2 * WORDS + dw];
            int p = s_roff[s2] + rel_off[s2 * WORDS + dw]
                  + __popc(cw & ((1u << (d & 31)) - 1u));
            atomicAdd(&oattr[(size_t)p * FDIM + 2 * q],     attr[(size_t)e * FDIM + 2 * q]);
            atomicAdd(&oattr[(size_t)p * FDIM + 2 * q + 1], attr[(size_t)e * FDIM + 2 * q + 1]);
        }
    }
}

extern "C" void kernel_launch(void* const* d_in, const int* in_sizes, int n_in,
                              void* d_out, int out_size, void* d_ws, size_t ws_size,
                              hipStream_t stream) {
    const int*   ei   = (const int*)d_in[1];     // [2, E]
    const float* attr = (const float*)d_in[2];   // [E, 8]
    int E = in_sizes[1] / 2;

    float* out = (float*)d_out;                  // rows | cols | attrs
    unsigned char* ws = (unsigned char*)d_ws;
    unsigned* a_bits  = (unsigned*)(ws);                          // 512 KB
    unsigned* c_bits  = (unsigned*)(ws + 512 * 1024);             // 512 KB
    int*      rel_off = (int*)(ws + 1024 * 1024);                 // 512 KB
    int*      row_cnt = (int*)(ws + 1536 * 1024);                 // 8 KB

    k_init_fill<<<2048, 256, 0, stream>>>(out, a_bits);

    void* args[] = { (void*)&ei, (void*)&attr, (void*)&E,
                     (void*)&a_bits, (void*)&c_bits, (void*)&rel_off,
                     (void*)&row_cnt, (void*)&out };
    hipLaunchCooperativeKernel((void*)k_fused, dim3(GRID2), dim3(256), args, 0, stream);
}

// Round 9
// 58.418 us; speedup vs baseline: 2.2382x; 2.2382x over previous
//
#include <hip/hip_runtime.h>

#define N_NODES 2048
#define WORDS   64          // N_NODES / 32
#define E_MAX_OUT 1048576
#define FDIM    8

// ws layout: a_bits(512K) | c_bits(512K) | rel_off(512K) | row_cnt(8K)

// ---------------- K1: output prefill (-1 idx / 0 attr) PARALLEL WITH bitset build ----------------
// Fill: branch-free float4 stream (R3-proven ~6.4 TB/s). Build: blocks 0..127 own 16 rows
// each; private LDS bitset, filter-scan of edge list, single coalesced writeback. No global
// atomics, no zero/build race, and build (~2us) hides under fill (~6.5us).
__global__ void __launch_bounds__(256) k1_fill_build(const int* __restrict__ ei, int E,
                                                     float* __restrict__ out,
                                                     unsigned* __restrict__ a_bits) {
    int b = blockIdx.x;
    int t = threadIdx.x;

    // output prefill slice (grid-stride, 2048*256 threads)
    const int TOTAL4 = (2 * E_MAX_OUT + FDIM * E_MAX_OUT) / 4;  // 2,621,440 float4
    const int NEG4   = (2 * E_MAX_OUT) / 4;                     // rows|cols = -1
    float4* o4 = (float4*)out;
    for (int p = b * 256 + t; p < TOTAL4; p += 2048 * 256) {
        float v = (p < NEG4) ? -1.0f : 0.0f;
        o4[p] = make_float4(v, v, v, v);
    }

    // bitset build for rows [b*16, b*16+16)
    if (b < 128) {
        __shared__ unsigned lbits[16 * WORDS];    // 4 KB
        for (int w = t; w < 16 * WORDS; w += 256) lbits[w] = 0u;
        __syncthreads();
        for (int e = t; e < E; e += 256) {
            int s = ei[e];
            int d = ei[E + e];
            if ((s >> 4) == b)
                atomicOr(&lbits[((s & 15) << 6) | (d >> 5)], 1u << (d & 31));
        }
        __syncthreads();
        uint4* g4 = (uint4*)(a_bits + b * 16 * WORDS);
        const uint4* l4 = (const uint4*)lbits;
        if (t < 16 * WORDS / 4) g4[t] = l4[t];
    }
}

// ---------------- K2: two-hop, one wave per row, 4 rows per block (proven) ----------------
__global__ void __launch_bounds__(256) k_twohop(const unsigned* __restrict__ a_bits,
                                                unsigned* __restrict__ c_bits,
                                                int* __restrict__ rel_off,
                                                int* __restrict__ row_cnt) {
    int lane = threadIdx.x & 63;
    int wv   = threadIdx.x >> 6;
    int i    = blockIdx.x * 4 + wv;
    __shared__ int nbr[4][256];
    __shared__ int ncnt_sh[4];

    unsigned r = a_bits[i * WORDS + lane];
    int pc = __popc(r);
    int incl = pc;
    for (int off = 1; off < 64; off <<= 1) {
        int v = __shfl_up(incl, off, 64);
        if (lane >= off) incl += v;
    }
    int base = incl - pc;
    unsigned bits = r;
    int wb = lane << 5;
    while (bits) {
        int b = __ffs(bits) - 1;
        bits &= bits - 1;
        nbr[wv][base++] = wb + b;
    }
    if (lane == 63) ncnt_sh[wv] = incl;
    __syncthreads();

    int nc = ncnt_sh[wv];
    const int* nb = nbr[wv];
    unsigned acc = 0u;
    int j = 0;
    for (; j + 4 <= nc; j += 4) {
        unsigned x0 = a_bits[nb[j]     * WORDS + lane];
        unsigned x1 = a_bits[nb[j + 1] * WORDS + lane];
        unsigned x2 = a_bits[nb[j + 2] * WORDS + lane];
        unsigned x3 = a_bits[nb[j + 3] * WORDS + lane];
        acc |= (x0 | x1) | (x2 | x3);
    }
    for (; j < nc; ++j) acc |= a_bits[nb[j] * WORDS + lane];

    if (lane == (i >> 5)) acc &= ~(1u << (i & 31));  // remove self-loop (two-hop)
    acc |= r;                                         // union original edges
    c_bits[i * WORDS + lane] = acc;

    int cnt = __popc(acc);
    int incl2 = cnt;
    for (int off = 1; off < 64; off <<= 1) {
        int v = __shfl_up(incl2, off, 64);
        if (lane >= off) incl2 += v;
    }
    rel_off[i * WORDS + lane] = incl2 - cnt;   // within-row exclusive word offset
    if (lane == 63) row_cnt[i] = incl2;
}

// ---------------- K3: full in-LDS scan + emit (coalesced) + atomic attr scatter ----------------
// Block i, 128 threads. Full 2048-entry exclusive scan in LDS gives row_off[s] for ANY s,
// so wave1 scatters attrs of edges [i*16, i*16+16) directly from ei (no elist needed) while
// wave0 stages row i's cols; then coalesced valid-index writes (tail was prefilled by K1).
__global__ void __launch_bounds__(128) k3_emit(const unsigned* __restrict__ c_bits,
                                               const int* __restrict__ rel_off,
                                               const int* __restrict__ row_cnt,
                                               const int* __restrict__ ei,
                                               const float* __restrict__ attr, int E,
                                               float* __restrict__ out) {
    int i    = blockIdx.x;
    int t    = threadIdx.x;
    int lane = t & 63;
    int wv   = t >> 6;
    __shared__ int s_roff[N_NODES];   // 8 KB
    __shared__ int s_cols[N_NODES];   // 8 KB
    __shared__ int wsum[2];

    // full exclusive scan of row_cnt into s_roff (16 values per thread)
    int vbase = t * (N_NODES / 128);
    int v16[N_NODES / 128];
    int s = 0;
    #pragma unroll
    for (int q = 0; q < N_NODES / 128; ++q) { v16[q] = row_cnt[vbase + q]; s += v16[q]; }
    int sincl = s;
    for (int off = 1; off < 64; off <<= 1) {
        int v = __shfl_up(sincl, off, 64);
        if (lane >= off) sincl += v;
    }
    if (lane == 63) wsum[wv] = sincl;
    __syncthreads();
    int run = ((wv == 1) ? wsum[0] : 0) + sincl - s;
    #pragma unroll
    for (int q = 0; q < N_NODES / 128; ++q) { s_roff[vbase + q] = run; run += v16[q]; }
    __syncthreads();

    int row_off_i = s_roff[i];
    int cnt_i     = row_cnt[i];

    if (wv == 0) {
        // stage cols of row i into LDS, in order
        unsigned c = c_bits[i * WORDS + lane];
        int base = rel_off[i * WORDS + lane];
        int wb = lane << 5;
        while (c) {
            int bb = __ffs(c) - 1;
            c &= c - 1;
            s_cols[base++] = wb + bb;
        }
    } else {
        // attr scatter: edges [i*16, i*16+16), 4 lanes per edge, O(1) rank
        float* oattr = out + 2 * E_MAX_OUT;
        int q = lane & 3;
        for (int e = i * 16 + (lane >> 2); e < E; e += N_NODES * 16) {
            int s2 = ei[e];
            int d  = ei[E + e];
            int dw = d >> 5;
            unsigned cw = c_bits[s2 * WORDS + dw];
            int p = s_roff[s2] + rel_off[s2 * WORDS + dw]
                  + __popc(cw & ((1u << (d & 31)) - 1u));
            atomicAdd(&oattr[(size_t)p * FDIM + 2 * q],     attr[(size_t)e * FDIM + 2 * q]);
            atomicAdd(&oattr[(size_t)p * FDIM + 2 * q + 1], attr[(size_t)e * FDIM + 2 * q + 1]);
        }
    }
    __syncthreads();

    // coalesced valid-index writes for row i
    float fi = (float)i;
    for (int j = t; j < cnt_i; j += 128) {
        int p = row_off_i + j;
        out[p]             = fi;
        out[E_MAX_OUT + p] = (float)s_cols[j];
    }
}

extern "C" void kernel_launch(void* const* d_in, const int* in_sizes, int n_in,
                              void* d_out, int out_size, void* d_ws, size_t ws_size,
                              hipStream_t stream) {
    const int*   ei   = (const int*)d_in[1];     // [2, E]
    const float* attr = (const float*)d_in[2];   // [E, 8]
    int E = in_sizes[1] / 2;

    float* out = (float*)d_out;                  // rows | cols | attrs
    unsigned char* ws = (unsigned char*)d_ws;
    unsigned* a_bits  = (unsigned*)(ws);                          // 512 KB
    unsigned* c_bits  = (unsigned*)(ws + 512 * 1024);             // 512 KB
    int*      rel_off = (int*)(ws + 1024 * 1024);                 // 512 KB
    int*      row_cnt = (int*)(ws + 1536 * 1024);                 // 8 KB

    k1_fill_build<<<2048, 256, 0, stream>>>(ei, E, out, a_bits);
    k_twohop     <<<N_NODES / 4, 256, 0, stream>>>(a_bits, c_bits, rel_off, row_cnt);
    k3_emit      <<<N_NODES, 128, 0, stream>>>(c_bits, rel_off, row_cnt, ei, attr, E, out);
}

// Round 10
// 29.828 us; speedup vs baseline: 4.3835x; 1.9585x over previous
//
#include <hip/hip_runtime.h>

#define N_NODES 2048
#define WORDS   64          // N_NODES / 32
#define E_MAX_OUT 1048576
#define FDIM    8

// ws layout: a_bits(512K) | c_bits(512K) | rel_off(512K) | row_cnt(8K)

// ---------------- K1: 40MB output prefill (-1 idx / 0 attr) + 1-edge-per-thread build ----------------
// Fill: branch-free float4 stream (R3-proven). Build: blocks 0..127, thread t handles edge
// b*256+t only (R3's proven ~1us k_build), hidden under the fill. a_bits pre-zeroed by memset.
__global__ void __launch_bounds__(256) k_fill_build(const int* __restrict__ ei, int E,
                                                    float* __restrict__ out,
                                                    unsigned* __restrict__ a_bits) {
    int b = blockIdx.x;
    int t = threadIdx.x;

    // build: one edge per thread (blocks 0..127 cover E=32768)
    int e = b * 256 + t;
    if (e < E) {
        int s = ei[e];
        int d = ei[E + e];
        atomicOr(&a_bits[s * WORDS + (d >> 5)], 1u << (d & 31));
    }

    // output prefill slice (grid-stride over 2,621,440 float4)
    const int TOTAL4 = (2 * E_MAX_OUT + FDIM * E_MAX_OUT) / 4;
    const int NEG4   = (2 * E_MAX_OUT) / 4;       // rows|cols region = -1
    float4* o4 = (float4*)out;
    for (int p = b * 256 + t; p < TOTAL4; p += 2048 * 256) {
        float v = (p < NEG4) ? -1.0f : 0.0f;
        o4[p] = make_float4(v, v, v, v);
    }
}

// ---------------- K2: two-hop, one wave per row, 4 rows per block (R3-proven) ----------------
__global__ void __launch_bounds__(256) k_twohop(const unsigned* __restrict__ a_bits,
                                                unsigned* __restrict__ c_bits,
                                                int* __restrict__ rel_off,
                                                int* __restrict__ row_cnt) {
    int lane = threadIdx.x & 63;
    int wv   = threadIdx.x >> 6;
    int i    = blockIdx.x * 4 + wv;
    __shared__ int nbr[4][256];
    __shared__ int ncnt_sh[4];

    unsigned r = a_bits[i * WORDS + lane];
    int pc = __popc(r);
    int incl = pc;
    for (int off = 1; off < 64; off <<= 1) {
        int v = __shfl_up(incl, off, 64);
        if (lane >= off) incl += v;
    }
    int base = incl - pc;
    unsigned bits = r;
    int wb = lane << 5;
    while (bits) {
        int b = __ffs(bits) - 1;
        bits &= bits - 1;
        nbr[wv][base++] = wb + b;
    }
    if (lane == 63) ncnt_sh[wv] = incl;
    __syncthreads();

    int nc = ncnt_sh[wv];
    const int* nb = nbr[wv];
    unsigned acc = 0u;
    int j = 0;
    for (; j + 4 <= nc; j += 4) {
        unsigned x0 = a_bits[nb[j]     * WORDS + lane];
        unsigned x1 = a_bits[nb[j + 1] * WORDS + lane];
        unsigned x2 = a_bits[nb[j + 2] * WORDS + lane];
        unsigned x3 = a_bits[nb[j + 3] * WORDS + lane];
        acc |= (x0 | x1) | (x2 | x3);
    }
    for (; j < nc; ++j) acc |= a_bits[nb[j] * WORDS + lane];

    if (lane == (i >> 5)) acc &= ~(1u << (i & 31));  // remove self-loop (two-hop)
    acc |= r;                                         // union original edges
    c_bits[i * WORDS + lane] = acc;

    int cnt = __popc(acc);
    int incl2 = cnt;
    for (int off = 1; off < 64; off <<= 1) {
        int v = __shfl_up(incl2, off, 64);
        if (lane >= off) incl2 += v;
    }
    rel_off[i * WORDS + lane] = incl2 - cnt;   // within-row exclusive word offset
    if (lane == 63) row_cnt[i] = incl2;
}

// ---------------- K3: full in-LDS scan + coalesced emit + O(1)-rank attr scatter (R9-proven) ----------------
__global__ void __launch_bounds__(128) k3_emit(const unsigned* __restrict__ c_bits,
                                               const int* __restrict__ rel_off,
                                               const int* __restrict__ row_cnt,
                                               const int* __restrict__ ei,
                                               const float* __restrict__ attr, int E,
                                               float* __restrict__ out) {
    int i    = blockIdx.x;
    int t    = threadIdx.x;
    int lane = t & 63;
    int wv   = t >> 6;
    __shared__ int s_roff[N_NODES];   // 8 KB
    __shared__ int s_cols[N_NODES];   // 8 KB
    __shared__ int wsum[2];

    // full exclusive scan of row_cnt into s_roff (16 values per thread)
    int vbase = t * (N_NODES / 128);
    int v16[N_NODES / 128];
    int s = 0;
    #pragma unroll
    for (int q = 0; q < N_NODES / 128; ++q) { v16[q] = row_cnt[vbase + q]; s += v16[q]; }
    int sincl = s;
    for (int off = 1; off < 64; off <<= 1) {
        int v = __shfl_up(sincl, off, 64);
        if (lane >= off) sincl += v;
    }
    if (lane == 63) wsum[wv] = sincl;
    __syncthreads();
    int run = ((wv == 1) ? wsum[0] : 0) + sincl - s;
    #pragma unroll
    for (int q = 0; q < N_NODES / 128; ++q) { s_roff[vbase + q] = run; run += v16[q]; }
    __syncthreads();

    int row_off_i = s_roff[i];
    int cnt_i     = row_cnt[i];

    if (wv == 0) {
        // stage cols of row i into LDS, in order
        unsigned c = c_bits[i * WORDS + lane];
        int base = rel_off[i * WORDS + lane];
        int wb = lane << 5;
        while (c) {
            int bb = __ffs(c) - 1;
            c &= c - 1;
            s_cols[base++] = wb + bb;
        }
    } else {
        // attr scatter: edges [i*16, i*16+16), 4 lanes per edge, O(1) rank
        float* oattr = out + 2 * E_MAX_OUT;
        int q = lane & 3;
        for (int e = i * 16 + (lane >> 2); e < E; e += N_NODES * 16) {
            int s2 = ei[e];
            int d  = ei[E + e];
            int dw = d >> 5;
            unsigned cw = c_bits[s2 * WORDS + dw];
            int p = s_roff[s2] + rel_off[s2 * WORDS + dw]
                  + __popc(cw & ((1u << (d & 31)) - 1u));
            atomicAdd(&oattr[(size_t)p * FDIM + 2 * q],     attr[(size_t)e * FDIM + 2 * q]);
            atomicAdd(&oattr[(size_t)p * FDIM + 2 * q + 1], attr[(size_t)e * FDIM + 2 * q + 1]);
        }
    }
    __syncthreads();

    // coalesced valid-index writes for row i (tail was prefilled by K1)
    float fi = (float)i;
    for (int j = t; j < cnt_i; j += 128) {
        int p = row_off_i + j;
        out[p]             = fi;
        out[E_MAX_OUT + p] = (float)s_cols[j];
    }
}

extern "C" void kernel_launch(void* const* d_in, const int* in_sizes, int n_in,
                              void* d_out, int out_size, void* d_ws, size_t ws_size,
                              hipStream_t stream) {
    const int*   ei   = (const int*)d_in[1];     // [2, E]
    const float* attr = (const float*)d_in[2];   // [E, 8]
    int E = in_sizes[1] / 2;

    float* out = (float*)d_out;                  // rows | cols | attrs
    unsigned char* ws = (unsigned char*)d_ws;
    unsigned* a_bits  = (unsigned*)(ws);                          // 512 KB
    unsigned* c_bits  = (unsigned*)(ws + 512 * 1024);             // 512 KB
    int*      rel_off = (int*)(ws + 1024 * 1024);                 // 512 KB
    int*      row_cnt = (int*)(ws + 1536 * 1024);                 // 8 KB

    hipMemsetAsync(a_bits, 0, N_NODES * WORDS * sizeof(unsigned), stream);
    k_fill_build<<<2048, 256, 0, stream>>>(ei, E, out, a_bits);
    k_twohop    <<<N_NODES / 4, 256, 0, stream>>>(a_bits, c_bits, rel_off, row_cnt);
    k3_emit     <<<N_NODES, 128, 0, stream>>>(c_bits, rel_off, row_cnt, ei, attr, E, out);
}

// Round 11
// 29.653 us; speedup vs baseline: 4.4094x; 1.0059x over previous
//
#include <hip/hip_runtime.h>

#define N_NODES 2048
#define WORDS   64          // N_NODES / 32
#define E_MAX_OUT 1048576
#define FDIM    8

// ws layout: a_bits(512K) | c_bits(512K) | rel_off(512K) | row_cnt(8K)

// ---------------- K1: 32MB attr-zero fill + 16-edges-per-block build ----------------
// a_bits pre-zeroed by hipMemsetAsync. Build spread across all 2048 blocks (16 edges each)
// so every block starts its fill slice immediately; -1 index prefill dropped (emit writes tail).
__global__ void __launch_bounds__(256) k_fill_build(const int* __restrict__ ei, int E,
                                                    float* __restrict__ oattr,
                                                    unsigned* __restrict__ a_bits) {
    int b = blockIdx.x;
    int t = threadIdx.x;

    // build: 16 edges per block, threads 0..15
    if (t < 16) {
        int e = b * 16 + t;
        if (e < E) {
            int s = ei[e];
            int d = ei[E + e];
            atomicOr(&a_bits[s * WORDS + (d >> 5)], 1u << (d & 31));
        }
    }

    // attr region zero-fill (grid-stride over 2,097,152 float4 = 32 MB)
    const int A4 = FDIM * E_MAX_OUT / 4;
    float4* o4 = (float4*)oattr;
    float4 z = make_float4(0.f, 0.f, 0.f, 0.f);
    for (int p = b * 256 + t; p < A4; p += 2048 * 256) o4[p] = z;
}

// ---------------- K2: two-hop, one wave per row, 4 rows per block (R3-proven) ----------------
__global__ void __launch_bounds__(256) k_twohop(const unsigned* __restrict__ a_bits,
                                                unsigned* __restrict__ c_bits,
                                                int* __restrict__ rel_off,
                                                int* __restrict__ row_cnt) {
    int lane = threadIdx.x & 63;
    int wv   = threadIdx.x >> 6;
    int i    = blockIdx.x * 4 + wv;
    __shared__ int nbr[4][256];
    __shared__ int ncnt_sh[4];

    unsigned r = a_bits[i * WORDS + lane];
    int pc = __popc(r);
    int incl = pc;
    for (int off = 1; off < 64; off <<= 1) {
        int v = __shfl_up(incl, off, 64);
        if (lane >= off) incl += v;
    }
    int base = incl - pc;
    unsigned bits = r;
    int wb = lane << 5;
    while (bits) {
        int b = __ffs(bits) - 1;
        bits &= bits - 1;
        nbr[wv][base++] = wb + b;
    }
    if (lane == 63) ncnt_sh[wv] = incl;
    __syncthreads();

    int nc = ncnt_sh[wv];
    const int* nb = nbr[wv];
    unsigned acc = 0u;
    int j = 0;
    for (; j + 4 <= nc; j += 4) {
        unsigned x0 = a_bits[nb[j]     * WORDS + lane];
        unsigned x1 = a_bits[nb[j + 1] * WORDS + lane];
        unsigned x2 = a_bits[nb[j + 2] * WORDS + lane];
        unsigned x3 = a_bits[nb[j + 3] * WORDS + lane];
        acc |= (x0 | x1) | (x2 | x3);
    }
    for (; j < nc; ++j) acc |= a_bits[nb[j] * WORDS + lane];

    if (lane == (i >> 5)) acc &= ~(1u << (i & 31));  // remove self-loop (two-hop)
    acc |= r;                                         // union original edges
    c_bits[i * WORDS + lane] = acc;

    int cnt = __popc(acc);
    int incl2 = cnt;
    for (int off = 1; off < 64; off <<= 1) {
        int v = __shfl_up(incl2, off, 64);
        if (lane >= off) incl2 += v;
    }
    rel_off[i * WORDS + lane] = incl2 - cnt;   // within-row exclusive word offset
    if (lane == 63) row_cnt[i] = incl2;
}

// ---------------- K3: in-LDS scan + coalesced emit + attr scatter + float4 tail ----------------
// 256 threads: full 2048-entry scan (8 vals/thread); wave0 stages cols, wave1 scatters attrs;
// then all 256 write valid indices + the block's grid-strided slice of the -1 tail.
__global__ void __launch_bounds__(256) k3_emit(const unsigned* __restrict__ c_bits,
                                               const int* __restrict__ rel_off,
                                               const int* __restrict__ row_cnt,
                                               const int* __restrict__ ei,
                                               const float* __restrict__ attr, int E,
                                               float* __restrict__ out) {
    int i    = blockIdx.x;
    int t    = threadIdx.x;
    int lane = t & 63;
    int wv   = t >> 6;
    __shared__ int s_roff[N_NODES];   // 8 KB
    __shared__ int s_cols[N_NODES];   // 8 KB
    __shared__ int wsum[4];

    // full exclusive scan of row_cnt into s_roff (8 values per thread)
    int vbase = t * (N_NODES / 256);
    int v8[N_NODES / 256];
    int s = 0;
    #pragma unroll
    for (int q = 0; q < N_NODES / 256; ++q) { v8[q] = row_cnt[vbase + q]; s += v8[q]; }
    int sincl = s;
    for (int off = 1; off < 64; off <<= 1) {
        int v = __shfl_up(sincl, off, 64);
        if (lane >= off) sincl += v;
    }
    if (lane == 63) wsum[wv] = sincl;
    __syncthreads();
    int woff = 0;
    for (int w = 0; w < wv; ++w) woff += wsum[w];
    int run = woff + sincl - s;
    #pragma unroll
    for (int q = 0; q < N_NODES / 256; ++q) { s_roff[vbase + q] = run; run += v8[q]; }
    int count = wsum[0] + wsum[1] + wsum[2] + wsum[3];
    __syncthreads();

    int row_off_i = s_roff[i];
    int cnt_i     = row_cnt[i];

    if (wv == 0) {
        // stage cols of row i into LDS, in order
        unsigned c = c_bits[i * WORDS + lane];
        int base = rel_off[i * WORDS + lane];
        int wb = lane << 5;
        while (c) {
            int bb = __ffs(c) - 1;
            c &= c - 1;
            s_cols[base++] = wb + bb;
        }
    } else if (wv == 1) {
        // attr scatter: edges [i*16, i*16+16), 4 lanes per edge, O(1) rank
        float* oattr = out + 2 * E_MAX_OUT;
        int q = lane & 3;
        for (int e = i * 16 + (lane >> 2); e < E; e += N_NODES * 16) {
            int s2 = ei[e];
            int d  = ei[E + e];
            int dw = d >> 5;
            unsigned cw = c_bits[s2 * WORDS + dw];
            int p = s_roff[s2] + rel_off[s2 * WORDS + dw]
                  + __popc(cw & ((1u << (d & 31)) - 1u));
            atomicAdd(&oattr[(size_t)p * FDIM + 2 * q],     attr[(size_t)e * FDIM + 2 * q]);
            atomicAdd(&oattr[(size_t)p * FDIM + 2 * q + 1], attr[(size_t)e * FDIM + 2 * q + 1]);
        }
    }
    __syncthreads();

    // coalesced valid-index writes for row i
    float fi = (float)i;
    for (int j = t; j < cnt_i; j += 256) {
        int p = row_off_i + j;
        out[p]             = fi;
        out[E_MAX_OUT + p] = (float)s_cols[j];
    }

    // -1 tail over [count, E_MAX_OUT): scalar head (block 0) + float4 grid-strided body
    int abase = (count + 3) & ~3;
    if (i == 0) {
        for (int p = count + t; p < abase; p += 256) {
            out[p]             = -1.0f;
            out[E_MAX_OUT + p] = -1.0f;
        }
    }
    float4 m4 = make_float4(-1.f, -1.f, -1.f, -1.f);
    float4* r4 = (float4*)out;
    float4* c4 = (float4*)(out + E_MAX_OUT);
    const int Q1 = E_MAX_OUT / 4;
    for (int q = abase / 4 + i * 256 + t; q < Q1; q += N_NODES * 256) {
        r4[q] = m4;
        c4[q] = m4;
    }
}

extern "C" void kernel_launch(void* const* d_in, const int* in_sizes, int n_in,
                              void* d_out, int out_size, void* d_ws, size_t ws_size,
                              hipStream_t stream) {
    const int*   ei   = (const int*)d_in[1];     // [2, E]
    const float* attr = (const float*)d_in[2];   // [E, 8]
    int E = in_sizes[1] / 2;

    float* out = (float*)d_out;                  // rows | cols | attrs
    unsigned char* ws = (unsigned char*)d_ws;
    unsigned* a_bits  = (unsigned*)(ws);                          // 512 KB
    unsigned* c_bits  = (unsigned*)(ws + 512 * 1024);             // 512 KB
    int*      rel_off = (int*)(ws + 1024 * 1024);                 // 512 KB
    int*      row_cnt = (int*)(ws + 1536 * 1024);                 // 8 KB

    hipMemsetAsync(a_bits, 0, N_NODES * WORDS * sizeof(unsigned), stream);
    k_fill_build<<<2048, 256, 0, stream>>>(ei, E, out + 2 * E_MAX_OUT, a_bits);
    k_twohop    <<<N_NODES / 4, 256, 0, stream>>>(a_bits, c_bits, rel_off, row_cnt);
    k3_emit     <<<N_NODES, 256, 0, stream>>>(c_bits, rel_off, row_cnt, ei, attr, E, out);
}